// Round 9
// baseline (252.190 us; speedup 1.0000x reference)
//
#include <hip/hip_runtime.h>
#include <hip/hip_bf16.h>
#include <hip/hip_fp16.h>
#include <hip/hip_cooperative_groups.h>

namespace cg = cooperative_groups;

// ESN cell update, MI355X. B=512, D=256, N=8192, NNZ=134217.
//
// 2-dispatch pipeline (R8 logic, dispatch-merged):
//   1. hipMemsetAsync: zero per-column counters (32 KB)
//   2. fused_k (cooperative, 1024 blocks = 4/CU):
//      Phase A: per block one 64x64 state-transpose tile (f32 -> fp16 b-pair
//        packed stateTh [N, B/2] uints); blocks 0..127 also one 32x32 input
//        transpose tile; blocks 128..652 also one 256-entry COO scatter chunk
//        (entry packed as (row<<16)|fp16(val), per-column buckets).
//      grid.sync()  (agent-scope fence: scatter/transpose visible cross-XCD)
//      Phase C: R8 spmm: slice = blockIdx&1 (256 b's, 4 MB fp16 -> XCD-L2
//        resident under round-robin), tile = blockIdx>>1 (16 cols). Wave owns
//        4 cols sequentially with exact mult-4-padded counts; per 4-entry
//        chunk one ds_read_b128 broadcast + 4 uint2 gathers + 2 v_pk_fma_f16
//        per entry. Epilogue: win + fast-tanh + leaky integrate -> tbuf
//        reshuffle -> coalesced float4 row-major out.
//
// R6 lesson: scalar-pipe uniform entry feed serializes the k-loop -> keep
// LDS-broadcast + wide TLP. R8 lesson: remaining controllable time is mostly
// dispatch gaps, hence this merge.
//
// Precision: fp16 state/vals; ~16-term accumulate ~1e-3 abs. Threshold
// 1.8e-2, observed absmax 3.9e-3.

#define ESN_B 512
#define ESN_D 256
#define ESN_N 8192
#define ESN_ALPHA 0.9f
#define CAP  128   // bucket capacity per column (Poisson(16.4): P(>128)~0)
#define LCAP 64    // LDS-staged capacity (P(nnz/col > 64) ~ 1e-20)
#define G    16    // columns per spmm block
#define NSLICE 2   // batch slices (256 b each, 4 MB fp16 per slice)

__device__ __forceinline__ unsigned pack_h2(float lo, float hi) {
    return (unsigned)__half_as_ushort(__float2half(lo)) |
           ((unsigned)__half_as_ushort(__float2half(hi)) << 16);
}

__device__ __forceinline__ __half2 int_as_h2(unsigned u) {
    union { unsigned i; __half2 h; } c; c.i = u; return c.h;
}

// duplicate the low 16 bits of e into both halves -> half2{val, val}
__device__ __forceinline__ __half2 duplo_h2(unsigned e) {
    return int_as_h2((e << 16) | (e & 0xFFFFu));
}

__device__ __forceinline__ float fast_tanh(float x) {
    x = fminf(fmaxf(x, -9.0f), 9.0f);
    const float e = __expf(2.0f * x);
    return (e - 1.0f) * __builtin_amdgcn_rcpf(e + 1.0f);
}

struct SmA {                       // phase A overlay (~12.7 KB)
    unsigned utile[64][33];        // [n-col][b-pair] packed fp16x2
    float    tile2[32][33];
};
struct SmC {                       // phase C overlay (~21 KB)
    unsigned ebuf[G][LCAP];        // per-col packed entry lists
    int      strue[G];
    int      spad[G];
    int      swr[G];
    float    sval[G], sbias[G];
    float    tbuf[G][260];         // [col][b-local] reshuffle
};

__global__ __launch_bounds__(256, 4) void fused_k(const float* __restrict__ state,
                                                  const float* __restrict__ inputs,
                                                  const int* __restrict__ wres_rows,
                                                  const int* __restrict__ wres_cols,
                                                  const float* __restrict__ wres_vals,
                                                  int* __restrict__ cnt,
                                                  unsigned* __restrict__ bucket,
                                                  unsigned* __restrict__ stateTh,
                                                  float* __restrict__ inputsT,
                                                  const float* __restrict__ win_vals,
                                                  const float* __restrict__ win_bias,
                                                  const int* __restrict__ win_rows,
                                                  float* __restrict__ out,
                                                  int nnz) {
    __shared__ union { SmA a; SmC c; } sm;
    const int blk = blockIdx.x;                 // 0..1023
    const int tid = threadIdx.x;

    // ---------------- Phase A: transposes + scatter ----------------
    {
        // state [512, 8192] f32 -> stateTh [8192, 256] uint (fp16 b-pairs)
        const int bx = blk & 127, by = blk >> 7;    // N/64 = 128 tiles in x
        const int c0 = bx * 64, r0 = by * 64;
        const int x = tid & 15, yp = tid >> 4;      // x: float4-col, yp: b-pair
#pragma unroll
        for (int i = 0; i < 2; ++i) {
            const int ypi = yp + 16 * i;            // b-pair 0..31
            const float4 v0 = *(const float4*)(state + (size_t)(r0 + 2 * ypi) * ESN_N + c0 + 4 * x);
            const float4 v1 = *(const float4*)(state + (size_t)(r0 + 2 * ypi + 1) * ESN_N + c0 + 4 * x);
            sm.a.utile[4 * x + 0][ypi] = pack_h2(v0.x, v1.x);
            sm.a.utile[4 * x + 1][ypi] = pack_h2(v0.y, v1.y);
            sm.a.utile[4 * x + 2][ypi] = pack_h2(v0.z, v1.z);
            sm.a.utile[4 * x + 3][ypi] = pack_h2(v0.w, v1.w);
        }
        __syncthreads();
        const int j = tid & 31, nn0 = tid >> 5;     // j: b-pair, nn0: n-row base
#pragma unroll
        for (int i = 0; i < 8; ++i) {
            const int nn = nn0 + 8 * i;
            stateTh[(size_t)(c0 + nn) * (ESN_B / 2) + (r0 >> 1) + j] = sm.a.utile[nn][j];
        }
    }
    if (blk < 128) {
        // inputs [512, 256] -> inputsT [256, 512] f32 (one 32x32 tile)
        const int bx = blk & 7, by = blk >> 3;
        const int tx = tid & 31, ty = tid >> 5;
        const int c0 = bx * 32, r0 = by * 32;
        __syncthreads();                            // tile2 fresh vs utile use
#pragma unroll
        for (int j = ty; j < 32; j += 8)
            sm.a.tile2[j][tx] = inputs[(size_t)(r0 + j) * ESN_D + c0 + tx];
        __syncthreads();
#pragma unroll
        for (int j = ty; j < 32; j += 8)
            inputsT[(size_t)(c0 + j) * ESN_B + r0 + tx] = sm.a.tile2[tx][j];
    } else {
        // COO scatter chunk; entry packed as (row << 16) | fp16(val)
        const int i = (blk - 128) * 256 + tid;
        if (blk - 128 < (nnz + 255) / 256 && i < nnz) {
            const int c = wres_cols[i];
            const int p = atomicAdd(&cnt[c], 1);
            if (p < CAP) {
                const unsigned h = (unsigned)__half_as_ushort(__float2half(wres_vals[i]));
                bucket[(size_t)c * CAP + p] = ((unsigned)wres_rows[i] << 16) | h;
            }
        }
    }

    cg::this_grid().sync();   // all transposes + scatters visible device-wide

    // ---------------- Phase C: spmm + epilogue ----------------
    const int slice = blk & (NSLICE - 1);          // -> XCD parity (round-robin)
    const int tile  = blk >> 1;
    const int c0 = tile * G;
    const int b0 = slice * 256;                    // this block's 256 b's
    const int lane = tid & 63;
    const int w    = tid >> 6;                     // wave 0..3 owns cols 4w..4w+3

    if (tid < G) {
        const int c = c0 + tid;
        int n = cnt[c];
        n = (n > LCAP) ? LCAP : n;
        sm.c.strue[tid] = n;
        sm.c.spad[tid]  = (n + 3) & ~3;
        sm.c.swr[tid]   = win_rows[c];
        sm.c.sval[tid]  = win_vals[c];
        sm.c.sbias[tid] = win_bias[c];
    }
    __syncthreads();

    // stage nnz lists, zero-padding the tail (zero entry: row 0, val 0 -> +0)
#pragma unroll
    for (int s = 0; s < G * LCAP; s += 256) {
        const int idx = s + tid;
        const int g = idx >> 6, k = idx & (LCAP - 1);
        sm.c.ebuf[g][k] = (k < sm.c.strue[g]) ? bucket[(size_t)(c0 + g) * CAP + k] : 0u;
    }
    __syncthreads();

    const uint2* __restrict__ strow2 = (const uint2*)stateTh;  // row = 128 uint2
    const unsigned boff = (unsigned)(slice * 64) + lane;       // uint2 idx in row

    // each wave: 4 columns sequentially, exact (mult-4-padded) counts
#pragma unroll
    for (int g = 4 * w; g < 4 * w + 4; ++g) {
        const int n4 = sm.c.spad[g];
        __half2 alo = int_as_h2(0u), ahi = alo;
        for (int k = 0; k < n4; k += 4) {
            const uint4 e = *(const uint4*)&sm.c.ebuf[g][k];  // 4 entries, bcast
            const uint2 p0 = strow2[((e.x >> 16) << 7) + boff];
            const uint2 p1 = strow2[((e.y >> 16) << 7) + boff];
            const uint2 p2 = strow2[((e.z >> 16) << 7) + boff];
            const uint2 p3 = strow2[((e.w >> 16) << 7) + boff];
            const __half2 v0 = duplo_h2(e.x), v1 = duplo_h2(e.y);
            const __half2 v2 = duplo_h2(e.z), v3 = duplo_h2(e.w);
            alo = __hfma2(int_as_h2(p0.x), v0, alo);
            ahi = __hfma2(int_as_h2(p0.y), v0, ahi);
            alo = __hfma2(int_as_h2(p1.x), v1, alo);
            ahi = __hfma2(int_as_h2(p1.y), v1, ahi);
            alo = __hfma2(int_as_h2(p2.x), v2, alo);
            ahi = __hfma2(int_as_h2(p2.y), v2, ahi);
            alo = __hfma2(int_as_h2(p3.x), v3, alo);
            ahi = __hfma2(int_as_h2(p3.y), v3, ahi);
        }

        // epilogue for column c0+g, this wave's 4 b's per lane
        const int c = c0 + g;
        const uint2 ps = strow2[((unsigned)c << 7) + boff];     // leak state
        const float s0 = __low2float(int_as_h2(ps.x)), s1 = __high2float(int_as_h2(ps.x));
        const float s2 = __low2float(int_as_h2(ps.y)), s3 = __high2float(int_as_h2(ps.y));
        const float4 inp = *(const float4*)(inputsT + (size_t)sm.c.swr[g] * ESN_B + b0 + 4 * lane);
        const float vv = sm.c.sval[g], bb = sm.c.sbias[g];
        float4 o;
        o.x = s0 + ESN_ALPHA * (fast_tanh(inp.x * vv + bb + __low2float(alo))  - s0);
        o.y = s1 + ESN_ALPHA * (fast_tanh(inp.y * vv + bb + __high2float(alo)) - s1);
        o.z = s2 + ESN_ALPHA * (fast_tanh(inp.z * vv + bb + __low2float(ahi))  - s2);
        o.w = s3 + ESN_ALPHA * (fast_tanh(inp.w * vv + bb + __high2float(ahi)) - s3);
        *(float4*)(&sm.c.tbuf[g][4 * lane]) = o;
    }
    __syncthreads();

    // reshuffle -> row-major out: 256 b-rows x 16 cols; lanes 0..3 cover one
    // 64 B run of a row -> coalesced float4 stores.
#pragma unroll
    for (int s = tid; s < 4 * 256; s += 256) {
        const int jj = s & 3;            // which float4 within the 16 cols
        const int bl = s >> 2;           // b-local 0..255
        const float4 o4 = make_float4(sm.c.tbuf[4 * jj + 0][bl], sm.c.tbuf[4 * jj + 1][bl],
                                      sm.c.tbuf[4 * jj + 2][bl], sm.c.tbuf[4 * jj + 3][bl]);
        *(float4*)(out + (size_t)(b0 + bl) * ESN_N + c0 + 4 * jj) = o4;
    }
}

extern "C" void kernel_launch(void* const* d_in, const int* in_sizes, int n_in,
                              void* d_out, int out_size, void* d_ws, size_t ws_size,
                              hipStream_t stream) {
    const float* inputs    = (const float*)d_in[0];  // [B, D]
    const float* state     = (const float*)d_in[1];  // [B, N]
    const float* win_vals  = (const float*)d_in[2];  // [N]
    const float* win_bias  = (const float*)d_in[3];  // [N]
    const float* wres_vals = (const float*)d_in[4];  // [NNZ]
    const int*   win_rows  = (const int*)d_in[5];    // [N]
    const int*   wres_rows = (const int*)d_in[6];    // [NNZ]
    const int*   wres_cols = (const int*)d_in[7];    // [NNZ]
    float* out = (float*)d_out;                      // [B, N]

    int NNZ = in_sizes[4];

    char* w = (char*)d_ws;
    unsigned* stateTh = (unsigned*)(w);                                  // 8 MB
    float*    inputsT = (float*)(w + (size_t)ESN_N * (ESN_B / 2) * 4);   // 512 KB
    unsigned* bucket  = (unsigned*)((char*)inputsT + (size_t)ESN_D * ESN_B * 4); // 4 MB
    int*      cnt     = (int*)((char*)bucket + (size_t)ESN_N * CAP * 4); // 32 KB

    hipMemsetAsync(cnt, 0, ESN_N * sizeof(int), stream);

    void* args[] = {(void*)&state, (void*)&inputs, (void*)&wres_rows,
                    (void*)&wres_cols, (void*)&wres_vals, (void*)&cnt,
                    (void*)&bucket, (void*)&stateTh, (void*)&inputsT,
                    (void*)&win_vals, (void*)&win_bias, (void*)&win_rows,
                    (void*)&out, (void*)&NNZ};
    hipLaunchCooperativeKernel((void*)fused_k, dim3(1024), dim3(256),
                               args, 0, stream);
}

// Round 10
// 109.655 us; speedup vs baseline: 2.2999x; 2.2999x over previous
//
#include <hip/hip_runtime.h>
#include <hip/hip_bf16.h>
#include <hip/hip_fp16.h>

// ESN cell update, MI355X. B=512, D=256, N=8192, NNZ=134217.
//
// 3-dispatch pipeline (R8 structure; R9's cooperative merge REGRESSED:
// ROCm grid.sync() spin-barrier cost >100 us for a ~15 us workload —
// dispatch boundaries are the cheap barrier on this runtime):
//   1. hipMemsetAsync: zero per-column counters (32 KB)
//   2. prep_k: state [B,N] f32 -> stateTh [N,B] fp16 (b-pairs packed in uint),
//      inputs -> inputsT f32, COO scatter (int4-vectorized reads, 4 entries
//      per lane) into per-column buckets; entry packed (row<<16)|fp16(val).
//   3. spmm_k: grid = (N/16 col-tiles) x 2 batch-slices of 256 b, 256 thr =
//      4 waves. Wave owns 4 columns sequentially with exact mult-4-padded
//      counts; per 4-entry chunk one ds_read_b128 broadcast + 4 uint2
//      gathers + 2 v_pk_fma_f16 per entry. slice = blockIdx&1 -> 4 MB fp16
//      b-slice per XCD (L2-resident under round-robin). Epilogue: win +
//      fast-tanh + leaky integrate -> tbuf reshuffle -> coalesced float4
//      row-major out.
//
// R6 lesson: scalar-pipe uniform entry feed serializes the k-loop -> keep
// LDS-broadcast + wide TLP.
//
// Precision: fp16 state/vals; ~16-term accumulate ~1e-3 abs. Threshold
// 1.8e-2, observed absmax 3.9e-3.

#define ESN_B 512
#define ESN_D 256
#define ESN_N 8192
#define ESN_ALPHA 0.9f
#define CAP  128   // bucket capacity per column (Poisson(16.4): P(>128)~0)
#define LCAP 64    // LDS-staged capacity (P(nnz/col > 64) ~ 1e-20)
#define G    16    // columns per spmm block
#define NSLICE 2   // batch slices (256 b each, 4 MB fp16 per slice)

__device__ __forceinline__ unsigned pack_h2(float lo, float hi) {
    return (unsigned)__half_as_ushort(__float2half(lo)) |
           ((unsigned)__half_as_ushort(__float2half(hi)) << 16);
}

__device__ __forceinline__ __half2 int_as_h2(unsigned u) {
    union { unsigned i; __half2 h; } c; c.i = u; return c.h;
}

// duplicate the low 16 bits of e into both halves -> half2{val, val}
__device__ __forceinline__ __half2 duplo_h2(unsigned e) {
    return int_as_h2((e << 16) | (e & 0xFFFFu));
}

__device__ __forceinline__ float fast_tanh(float x) {
    x = fminf(fmaxf(x, -9.0f), 9.0f);
    const float e = __expf(2.0f * x);
    return (e - 1.0f) * __builtin_amdgcn_rcpf(e + 1.0f);
}

__device__ __forceinline__ void scat1(int* cnt, unsigned* bucket, int c, int r, float v) {
    const int p = atomicAdd(&cnt[c], 1);
    if (p < CAP) {
        const unsigned h = (unsigned)__half_as_ushort(__float2half(v));
        bucket[(size_t)c * CAP + p] = ((unsigned)r << 16) | h;
    }
}

__global__ __launch_bounds__(256) void prep_k(const float* __restrict__ state,
                                              const float* __restrict__ inputs,
                                              const int* __restrict__ wres_rows,
                                              const int* __restrict__ wres_cols,
                                              const float* __restrict__ wres_vals,
                                              int* __restrict__ cnt,
                                              unsigned* __restrict__ bucket,
                                              unsigned* __restrict__ stateTh,
                                              float* __restrict__ inputsT,
                                              int nnz) {
    __shared__ unsigned utile[64][33];   // [n-col][b-pair] packed fp16x2
    __shared__ float    tile2[32][33];
    const int t = blockIdx.x;
    const int tid = threadIdx.x;
    const int NB_TS = (ESN_N / 64) * (ESN_B / 64);  // 1024 state tiles (64x64)
    const int NB_TI = (ESN_D / 32) * (ESN_B / 32);  // 128 input tiles

    if (t < NB_TS) {
        // state [512, 8192] f32 -> stateTh [8192, 256] uint (fp16 b-pairs)
        const int bx = t & 127, by = t >> 7;        // N/64 = 128 tiles in x
        const int c0 = bx * 64, r0 = by * 64;
        const int x = tid & 15, yp = tid >> 4;      // x: float4-col, yp: b-pair
#pragma unroll
        for (int i = 0; i < 2; ++i) {
            const int ypi = yp + 16 * i;            // b-pair 0..31
            const float4 v0 = *(const float4*)(state + (size_t)(r0 + 2 * ypi) * ESN_N + c0 + 4 * x);
            const float4 v1 = *(const float4*)(state + (size_t)(r0 + 2 * ypi + 1) * ESN_N + c0 + 4 * x);
            utile[4 * x + 0][ypi] = pack_h2(v0.x, v1.x);
            utile[4 * x + 1][ypi] = pack_h2(v0.y, v1.y);
            utile[4 * x + 2][ypi] = pack_h2(v0.z, v1.z);
            utile[4 * x + 3][ypi] = pack_h2(v0.w, v1.w);
        }
        __syncthreads();
        const int j = tid & 31, nn0 = tid >> 5;     // j: b-pair, nn0: n-row base
#pragma unroll
        for (int i = 0; i < 8; ++i) {
            const int nn = nn0 + 8 * i;
            stateTh[(size_t)(c0 + nn) * (ESN_B / 2) + (r0 >> 1) + j] = utile[nn][j];
        }
    } else if (t < NB_TS + NB_TI) {
        // inputs [512, 256] -> inputsT [256, 512] f32
        const int t2 = t - NB_TS;
        const int bx = t2 & 7, by = t2 >> 3;
        const int tx = tid & 31, ty = tid >> 5;
        const int c0 = bx * 32, r0 = by * 32;
#pragma unroll
        for (int j = ty; j < 32; j += 8)
            tile2[j][tx] = inputs[(size_t)(r0 + j) * ESN_D + c0 + tx];
        __syncthreads();
#pragma unroll
        for (int j = ty; j < 32; j += 8)
            inputsT[(size_t)(c0 + j) * ESN_B + r0 + tx] = tile2[tx][j];
    } else {
        // COO scatter, int4-vectorized: 4 entries per lane
        const int q = (t - NB_TS - NB_TI) * 256 + tid;   // quad index
        const int nfull = nnz >> 2;                      // full quads
        if (q < nfull) {
            const int4   r4 = *(const int4*)(wres_rows + 4 * q);
            const int4   c4 = *(const int4*)(wres_cols + 4 * q);
            const float4 v4 = *(const float4*)(wres_vals + 4 * q);
            scat1(cnt, bucket, c4.x, r4.x, v4.x);
            scat1(cnt, bucket, c4.y, r4.y, v4.y);
            scat1(cnt, bucket, c4.z, r4.z, v4.z);
            scat1(cnt, bucket, c4.w, r4.w, v4.w);
        } else if (q == nfull) {
            for (int i = 4 * nfull; i < nnz; ++i)        // tail (<4 entries)
                scat1(cnt, bucket, wres_cols[i], wres_rows[i], wres_vals[i]);
        }
    }
}

__global__ __launch_bounds__(256, 4) void spmm_k(const int* __restrict__ cnt,
                                                 const unsigned* __restrict__ bucket,
                                                 const unsigned* __restrict__ stateTh,
                                                 const float* __restrict__ inputsT,
                                                 const float* __restrict__ win_vals,
                                                 const float* __restrict__ win_bias,
                                                 const int* __restrict__ win_rows,
                                                 float* __restrict__ out) {
    const int slice = blockIdx.x & (NSLICE - 1);   // -> XCD parity (round-robin)
    const int tile  = blockIdx.x >> 1;
    const int c0 = tile * G;
    const int b0 = slice * 256;                    // this block's 256 b's
    const int lane = threadIdx.x & 63;
    const int w    = threadIdx.x >> 6;             // wave 0..3 owns cols 4w..4w+3

    __shared__ unsigned ebuf[G][LCAP];             // per-col packed entry lists
    __shared__ int   strue[G];                     // exact counts (staging)
    __shared__ int   spad[G];                      // counts padded to mult of 4
    __shared__ int   swr[G];
    __shared__ float sval[G], sbias[G];
    __shared__ float tbuf[G][260];                 // [col][b-local] reshuffle

    if (threadIdx.x < G) {
        const int c = c0 + threadIdx.x;
        int n = cnt[c];
        n = (n > LCAP) ? LCAP : n;
        strue[threadIdx.x] = n;
        spad[threadIdx.x]  = (n + 3) & ~3;
        swr[threadIdx.x]   = win_rows[c];
        sval[threadIdx.x]  = win_vals[c];
        sbias[threadIdx.x] = win_bias[c];
    }
    __syncthreads();

    // stage nnz lists, zero-padding the tail (zero entry: row 0, val 0 -> +0)
#pragma unroll
    for (int s = 0; s < G * LCAP; s += 256) {
        const int idx = s + threadIdx.x;
        const int g = idx >> 6, k = idx & (LCAP - 1);
        ebuf[g][k] = (k < strue[g]) ? bucket[(size_t)(c0 + g) * CAP + k] : 0u;
    }
    __syncthreads();

    const uint2* __restrict__ strow2 = (const uint2*)stateTh;  // row = 128 uint2
    const unsigned boff = (unsigned)(slice * 64) + lane;       // uint2 idx in row

    // each wave: 4 columns sequentially, exact (mult-4-padded) counts
#pragma unroll
    for (int g = 4 * w; g < 4 * w + 4; ++g) {
        const int n4 = spad[g];
        __half2 alo = int_as_h2(0u), ahi = alo;
        for (int k = 0; k < n4; k += 4) {
            const uint4 e = *(const uint4*)&ebuf[g][k];  // 4 entries, broadcast
            const uint2 p0 = strow2[((e.x >> 16) << 7) + boff];
            const uint2 p1 = strow2[((e.y >> 16) << 7) + boff];
            const uint2 p2 = strow2[((e.z >> 16) << 7) + boff];
            const uint2 p3 = strow2[((e.w >> 16) << 7) + boff];
            const __half2 v0 = duplo_h2(e.x), v1 = duplo_h2(e.y);
            const __half2 v2 = duplo_h2(e.z), v3 = duplo_h2(e.w);
            alo = __hfma2(int_as_h2(p0.x), v0, alo);
            ahi = __hfma2(int_as_h2(p0.y), v0, ahi);
            alo = __hfma2(int_as_h2(p1.x), v1, alo);
            ahi = __hfma2(int_as_h2(p1.y), v1, ahi);
            alo = __hfma2(int_as_h2(p2.x), v2, alo);
            ahi = __hfma2(int_as_h2(p2.y), v2, ahi);
            alo = __hfma2(int_as_h2(p3.x), v3, alo);
            ahi = __hfma2(int_as_h2(p3.y), v3, ahi);
        }

        // epilogue for column c0+g, this wave's 4 b's per lane
        const int c = c0 + g;
        const uint2 ps = strow2[((unsigned)c << 7) + boff];     // leak state
        const float s0 = __low2float(int_as_h2(ps.x)), s1 = __high2float(int_as_h2(ps.x));
        const float s2 = __low2float(int_as_h2(ps.y)), s3 = __high2float(int_as_h2(ps.y));
        const float4 inp = *(const float4*)(inputsT + (size_t)swr[g] * ESN_B + b0 + 4 * lane);
        const float vv = sval[g], bb = sbias[g];
        float4 o;
        o.x = s0 + ESN_ALPHA * (fast_tanh(inp.x * vv + bb + __low2float(alo))  - s0);
        o.y = s1 + ESN_ALPHA * (fast_tanh(inp.y * vv + bb + __high2float(alo)) - s1);
        o.z = s2 + ESN_ALPHA * (fast_tanh(inp.z * vv + bb + __low2float(ahi))  - s2);
        o.w = s3 + ESN_ALPHA * (fast_tanh(inp.w * vv + bb + __high2float(ahi)) - s3);
        *(float4*)(&tbuf[g][4 * lane]) = o;
    }
    __syncthreads();

    // reshuffle -> row-major out: 256 b-rows x 16 cols; lanes 0..3 cover one
    // 64 B run of a row -> coalesced float4 stores.
#pragma unroll
    for (int s = threadIdx.x; s < 4 * 256; s += 256) {
        const int jj = s & 3;            // which float4 within the 16 cols
        const int bl = s >> 2;           // b-local 0..255
        const float4 o4 = make_float4(tbuf[4 * jj + 0][bl], tbuf[4 * jj + 1][bl],
                                      tbuf[4 * jj + 2][bl], tbuf[4 * jj + 3][bl]);
        *(float4*)(out + (size_t)(b0 + bl) * ESN_N + c0 + 4 * jj) = o4;
    }
}

extern "C" void kernel_launch(void* const* d_in, const int* in_sizes, int n_in,
                              void* d_out, int out_size, void* d_ws, size_t ws_size,
                              hipStream_t stream) {
    const float* inputs    = (const float*)d_in[0];  // [B, D]
    const float* state     = (const float*)d_in[1];  // [B, N]
    const float* win_vals  = (const float*)d_in[2];  // [N]
    const float* win_bias  = (const float*)d_in[3];  // [N]
    const float* wres_vals = (const float*)d_in[4];  // [NNZ]
    const int*   win_rows  = (const int*)d_in[5];    // [N]
    const int*   wres_rows = (const int*)d_in[6];    // [NNZ]
    const int*   wres_cols = (const int*)d_in[7];    // [NNZ]
    float* out = (float*)d_out;                      // [B, N]

    const int NNZ = in_sizes[4];

    char* w = (char*)d_ws;
    unsigned* stateTh = (unsigned*)(w);                                  // 8 MB
    float*    inputsT = (float*)(w + (size_t)ESN_N * (ESN_B / 2) * 4);   // 512 KB
    unsigned* bucket  = (unsigned*)((char*)inputsT + (size_t)ESN_D * ESN_B * 4); // 4 MB
    int*      cnt     = (int*)((char*)bucket + (size_t)ESN_N * CAP * 4); // 32 KB

    hipMemsetAsync(cnt, 0, ESN_N * sizeof(int), stream);

    const int nb_sc = ((NNZ >> 2) + 1 + 255) / 256;   // quads + tail lane
    const int nb = (ESN_N / 64) * (ESN_B / 64) + (ESN_D / 32) * (ESN_B / 32) + nb_sc;
    prep_k<<<nb, 256, 0, stream>>>(state, inputs, wres_rows, wres_cols, wres_vals,
                                   cnt, bucket, stateTh, inputsT, NNZ);

    spmm_k<<<(ESN_N / G) * NSLICE, 256, 0, stream>>>(cnt, bucket, stateTh, inputsT,
                                                     win_vals, win_bias, win_rows, out);
}